// Round 7
// baseline (401.256 us; speedup 1.0000x reference)
//
#include <hip/hip_runtime.h>

#define DBITS 18

typedef float v2f __attribute__((ext_vector_type(2)));

// LDS physical swizzle for float2 (b64) accesses. GF(2)-linear. Low-4 images:
// j0-3 -> e0-3; j4->e1, j5->e2, j6->e0^e3, j8->e2, j9->e3; j7,j10-12 -> 0.
// Verified: every round's 16-lane-group varying j-bits have rank-4 images.
__device__ __forceinline__ constexpr int physb(int j){
  return j ^ (((j>>4)&1)<<1) ^ (((j>>5)&1)<<2) ^ (((j>>6)&1)<<3) ^ (((j>>6)&1)<<0)
           ^ (((j>>8)&1)<<2) ^ (((j>>9)&1)<<3);
}
template<int b0,int b1,int b2>
__device__ __forceinline__ int dep3(int c){
  return ((c&1)<<b0) | (((c>>1)&1)<<b1) | (((c>>2)&1)<<b2);
}
template<int b0,int b1,int b2>
__device__ __forceinline__ int pb3(int c){ return physb(dep3<b0,b1,b2>(c)); }

// manual RNE pack for global bf16 hops
__device__ __forceinline__ unsigned pack_bf2(v2f v){
  unsigned ur = __float_as_uint(v.x), ui = __float_as_uint(v.y);
  ur = (ur + 0x7FFFu + ((ur >> 16) & 1u)) >> 16;
  ui = (ui + 0x7FFFu + ((ui >> 16) & 1u)) & 0xFFFF0000u;
  return ur | ui;
}
__device__ __forceinline__ v2f unpack_bf2(unsigned u){
  v2f v; v.x = __uint_as_float(u << 16); v.y = __uint_as_float(u & 0xFFFF0000u); return v;
}

// ---- packed f32 complex helpers (v_pk_fma_f32 with op_sel swap tricks) ----
__device__ __forceinline__ v2f pk_mul(v2f x, v2f s){
  v2f r; asm("v_pk_mul_f32 %0, %1, %2" : "=v"(r) : "v"(x), "v"(s)); return r;
}
__device__ __forceinline__ v2f pk_mul_neg(v2f x, v2f s){
  v2f r; asm("v_pk_mul_f32 %0, %1, %2 neg_lo:[1,0] neg_hi:[1,0]" : "=v"(r) : "v"(x), "v"(s)); return r;
}
__device__ __forceinline__ v2f pk_fma(v2f x, v2f s, v2f a){
  v2f r; asm("v_pk_fma_f32 %0, %1, %2, %3" : "=v"(r) : "v"(x), "v"(s), "v"(a)); return r;
}
// r = s * (-x.hi, x.lo) + a
__device__ __forceinline__ v2f pk_fma_swlo(v2f x, v2f s, v2f a){
  v2f r; asm("v_pk_fma_f32 %0, %1, %2, %3 op_sel:[1,0,0] op_sel_hi:[0,1,1] neg_lo:[1,0,0]"
             : "=v"(r) : "v"(x), "v"(s), "v"(a)); return r;
}
// r = s * (x.hi, -x.lo) + a
__device__ __forceinline__ v2f pk_fma_swhi(v2f x, v2f s, v2f a){
  v2f r; asm("v_pk_fma_f32 %0, %1, %2, %3 op_sel:[1,0,0] op_sel_hi:[0,1,1] neg_hi:[1,0,0]"
             : "=v"(r) : "v"(x), "v"(s), "v"(a)); return r;
}

// SU(2) gate U=[[a,b],[-conj(b),conj(a)]], g={Ar,Ai,Br,Bi}; 8 amps/thread.
template<int S>
__device__ __forceinline__ void gate_pk8(v2f a[8], const float* __restrict__ g){
  const v2f Ar = {g[0],g[0]}, Ai = {g[1],g[1]}, Br = {g[2],g[2]}, Bi = {g[3],g[3]};
  #pragma unroll
  for (int h = 0; h < 4; ++h){
    const int c0 = ((h & ~(S-1)) << 1) | (h & (S-1));
    const int c1 = c0 | S;
    const v2f X0 = a[c0], X1 = a[c1];
    v2f y0 = pk_mul(X0, Ar);
    y0 = pk_fma_swlo(X0, Ai, y0);
    y0 = pk_fma(X1, Br, y0);
    y0 = pk_fma_swlo(X1, Bi, y0);
    v2f y1 = pk_mul_neg(X0, Br);
    y1 = pk_fma_swlo(X0, Bi, y1);
    y1 = pk_fma(X1, Ar, y1);
    y1 = pk_fma_swhi(X1, Ai, y1);
    a[c0] = y0; a[c1] = y1;
  }
}

template<int CTRL>
__device__ __forceinline__ float dppf(float v){
  return __int_as_float(__builtin_amdgcn_update_dpp(0, __float_as_int(v), CTRL, 0xF, 0xF, true));
}
// Gate on lane bit t0 (0xB1) or t1 (0x4E); s=-1 when the lane's bit is set.
template<int CTRL>
__device__ __forceinline__ void gate_lane8(v2f a[8], const float* __restrict__ g, float s){
  const float uei = s*g[1], uor = s*g[2];
  const v2f UER = {g[0],g[0]}, UEI = {uei,uei}, UOR = {uor,uor}, UOI = {g[3],g[3]};
  #pragma unroll
  for (int c = 0; c < 8; ++c){
    const v2f X = a[c];
    v2f P; P.x = dppf<CTRL>(X.x); P.y = dppf<CTRL>(X.y);
    v2f y = pk_mul(X, UER);
    y = pk_fma_swlo(X, UEI, y);
    y = pk_fma(P, UOR, y);
    y = pk_fma_swlo(P, UOI, y);
    a[c] = y;
  }
}

__device__ __forceinline__ const float* gp(const float* __restrict__ gates, int L, int ggbit){
  return gates + (L*18 + (17 - ggbit))*4;
}
__device__ __forceinline__ void sgn(v2f& v, unsigned gg){
  const unsigned sb = (unsigned)(__popc(gg & (gg >> 1)) & 1) << 31;
  v.x = __uint_as_float(__float_as_uint(v.x) ^ sb);
  v.y = __uint_as_float(__float_as_uint(v.y) ^ sb);
}

// ===== Ledger (each (layer, gg-bit) exactly once) =====
// P1 (W1=gg0-12, f=gg13-17): R1 L1 c gg0,1,2 + dpp gg3,4 | R2 L1 c gg5,6,7 + dpp gg8,9
//                            R3 L1 c gg10,11,12; store
// P2 (W2=gg0-7,13-17, f=gg8-12): R1 L1 c gg15,16,17 + dpp gg13,14; sign1;
//                            L2 c gg15,16,17 + dpp gg13,14 | R2 L2 c gg0,1,2 + dpp gg3,4
//                            R3 L2 c gg5,6,7; store  (L2 leftover = gg8-12)
// P3 (W3=gg0-12, f=gg13-17): R1 L2 c gg10,11,12 + dpp gg8,9; sign2;
//                            L3 c gg10,11,12 + dpp gg8,9 | R2 L3 c gg2,3,4 + dpp gg0,1
//                            R3 L3 c gg5,6,7; store  (L3 leftover = gg13-17)
// P4 (W4=W2): R1 L3 c gg15,16,17 + dpp gg13,14; fused head (single round, no LDS exchange)
// Final CZ layer absorbed by |amp|^2.
template<int PASS>
__global__ __launch_bounds__(1024, 8)
void qpass(const float* __restrict__ sr, const float* __restrict__ si,
           unsigned* __restrict__ st, const float* __restrict__ gates,
           const float* __restrict__ head_w, float* __restrict__ partials,
           int batch0)
{
  __shared__ v2f lds[8192];   // 64 KiB f32 pairs
  const int t = threadIdx.x;

  // XCD-aware bijective swizzle: consecutive logical ids share an XCD
  const int nwg = (int)gridDim.x;
  const int p = (int)blockIdx.x;
  const int q = nwg >> 3, r = nwg & 7, x = p & 7, m = p >> 3;
  const int logical = (x < r ? x*(q+1) : r*(q+1) + (x-r)*q) + m;
  const int f  = logical & 31;
  const int bl = logical >> 5;
  const int bg = batch0 + bl;
  const unsigned stBase = ((unsigned)bl) << DBITS;
  const size_t  inBase  = ((size_t)bg) << DBITS;
  const float s1 = (t & 1) ? -1.f : 1.f;
  const float s2 = (t & 2) ? -1.f : 1.f;

  v2f a[8];

  if (PASS == 1){
    // ---- R1: c->j0-2; t0,t1->j3,j4 (dpp gg3,4); t2-9->j5-12. float4 loads ----
    {
      const int jb = ((t&1)<<3) | (((t>>1)&1)<<4) | ((t>>2)<<5);
      const size_t base = inBase + ((size_t)f << 13) + (size_t)jb;
      const float4 r0 = *(const float4*)(sr+base);
      const float4 r1 = *(const float4*)(sr+base+4);
      const float4 i0 = *(const float4*)(si+base);
      const float4 i1 = *(const float4*)(si+base+4);
      a[0] = {r0.x,i0.x}; a[1] = {r0.y,i0.y}; a[2] = {r0.z,i0.z}; a[3] = {r0.w,i0.w};
      a[4] = {r1.x,i1.x}; a[5] = {r1.y,i1.y}; a[6] = {r1.z,i1.z}; a[7] = {r1.w,i1.w};
      gate_pk8<1>(a, gp(gates,0,0));
      gate_pk8<2>(a, gp(gates,0,1));
      gate_pk8<4>(a, gp(gates,0,2));
      gate_lane8<0xB1>(a, gp(gates,0,3), s1);
      gate_lane8<0x4E>(a, gp(gates,0,4), s2);
      const int pj = physb(jb);
      #pragma unroll
      for (int c = 0; c < 8; ++c) lds[pj ^ pb3<0,1,2>(c)] = a[c];
    }
    __syncthreads();
    // ---- R2: c->j5-7; t0,t1->j8,j9 (dpp gg8,9); t2-5->j0-3, t6->j4, t7-9->j10-12 ----
    {
      const int jb = ((t&1)<<8)|(((t>>1)&1)<<9)|(((t>>2)&1)<<0)|(((t>>3)&1)<<1)
                   | (((t>>4)&1)<<2)|(((t>>5)&1)<<3)|(((t>>6)&1)<<4)
                   | (((t>>7)&1)<<10)|(((t>>8)&1)<<11)|(((t>>9)&1)<<12);
      const int pj = physb(jb);
      #pragma unroll
      for (int c = 0; c < 8; ++c) a[c] = lds[pj ^ pb3<5,6,7>(c)];
      gate_pk8<1>(a, gp(gates,0,5));
      gate_pk8<2>(a, gp(gates,0,6));
      gate_pk8<4>(a, gp(gates,0,7));
      gate_lane8<0xB1>(a, gp(gates,0,8), s1);
      gate_lane8<0x4E>(a, gp(gates,0,9), s2);
      #pragma unroll
      for (int c = 0; c < 8; ++c) lds[pj ^ pb3<5,6,7>(c)] = a[c];
    }
    __syncthreads();
    // ---- R3: c->j10-12; t->j0-9; store bf16 ----
    {
      const int pj = physb(t);
      #pragma unroll
      for (int c = 0; c < 8; ++c) a[c] = lds[pj ^ pb3<10,11,12>(c)];
      gate_pk8<1>(a, gp(gates,0,10));
      gate_pk8<2>(a, gp(gates,0,11));
      gate_pk8<4>(a, gp(gates,0,12));
      const unsigned gb = stBase + (unsigned)((f<<13) | t);
      #pragma unroll
      for (int c = 0; c < 8; ++c) st[gb + ((unsigned)c<<10)] = pack_bf2(a[c]);
    }
  }
  else if (PASS == 2){
    // ---- R1: t0,t1->j8,j9 (gg13,14 dpp); t2-9->j0-7; c->j10-12 (gg15,16,17) ----
    {
      const int jb = ((t&1)<<8)|(((t>>1)&1)<<9)|((t>>2)&255);
      const unsigned gg0 = (unsigned)((jb&255) | ((jb>>8)<<13) | (f<<8));
      const unsigned gb = stBase + gg0;
      #pragma unroll
      for (int c = 0; c < 8; ++c) a[c] = unpack_bf2(st[gb + ((unsigned)c<<15)]);
      // L1 tail
      gate_pk8<1>(a, gp(gates,0,15));
      gate_pk8<2>(a, gp(gates,0,16));
      gate_pk8<4>(a, gp(gates,0,17));
      gate_lane8<0xB1>(a, gp(gates,0,13), s1);
      gate_lane8<0x4E>(a, gp(gates,0,14), s2);
      // sign1 (L1 complete)
      #pragma unroll
      for (int c = 0; c < 8; ++c) sgn(a[c], gg0 + ((unsigned)c<<15));
      // L2 head (same addressable bits)
      gate_pk8<1>(a, gp(gates,1,15));
      gate_pk8<2>(a, gp(gates,1,16));
      gate_pk8<4>(a, gp(gates,1,17));
      gate_lane8<0xB1>(a, gp(gates,1,13), s1);
      gate_lane8<0x4E>(a, gp(gates,1,14), s2);
      const int pj = physb(jb);
      #pragma unroll
      for (int c = 0; c < 8; ++c) lds[pj ^ pb3<10,11,12>(c)] = a[c];
    }
    __syncthreads();
    // ---- R2: c->j0-2 (gg0,1,2); t0,t1->j3,j4 (dpp gg3,4); t2-9->j5-12 ----
    {
      const int jb = ((t&1)<<3) | (((t>>1)&1)<<4) | ((t>>2)<<5);
      const int pj = physb(jb);
      #pragma unroll
      for (int c = 0; c < 8; ++c) a[c] = lds[pj ^ pb3<0,1,2>(c)];
      gate_pk8<1>(a, gp(gates,1,0));
      gate_pk8<2>(a, gp(gates,1,1));
      gate_pk8<4>(a, gp(gates,1,2));
      gate_lane8<0xB1>(a, gp(gates,1,3), s1);
      gate_lane8<0x4E>(a, gp(gates,1,4), s2);
      #pragma unroll
      for (int c = 0; c < 8; ++c) lds[pj ^ pb3<0,1,2>(c)] = a[c];
    }
    __syncthreads();
    // ---- R3: c->j5-7 (gg5,6,7); t0-4->j0-4, t5-9->j8-12; store ----
    {
      const int jb = (t&31) | (((t>>5)&31)<<8);
      const int pj = physb(jb);
      #pragma unroll
      for (int c = 0; c < 8; ++c) a[c] = lds[pj ^ pb3<5,6,7>(c)];
      gate_pk8<1>(a, gp(gates,1,5));
      gate_pk8<2>(a, gp(gates,1,6));
      gate_pk8<4>(a, gp(gates,1,7));
      #pragma unroll
      for (int c = 0; c < 8; ++c){
        const int j = jb | dep3<5,6,7>(c);
        st[stBase + (unsigned)((j&255) | ((j>>8)<<13) | (f<<8))] = pack_bf2(a[c]);
      }
    }
  }
  else if (PASS == 3){
    // ---- R1: t0,t1->j8,j9 (dpp gg8,9); t2-9->j0-7; c->j10-12 ----
    {
      const int jb = ((t&1)<<8)|(((t>>1)&1)<<9)|((t>>2)&255);
      const unsigned gg0 = (unsigned)(jb | (f<<13));
      const unsigned gb = stBase + gg0;
      #pragma unroll
      for (int c = 0; c < 8; ++c) a[c] = unpack_bf2(st[gb + ((unsigned)c<<10)]);
      // L2 tail
      gate_pk8<1>(a, gp(gates,1,10));
      gate_pk8<2>(a, gp(gates,1,11));
      gate_pk8<4>(a, gp(gates,1,12));
      gate_lane8<0xB1>(a, gp(gates,1,8), s1);
      gate_lane8<0x4E>(a, gp(gates,1,9), s2);
      // sign2 (L2 complete)
      #pragma unroll
      for (int c = 0; c < 8; ++c) sgn(a[c], gg0 + ((unsigned)c<<10));
      // L3 head
      gate_pk8<1>(a, gp(gates,2,10));
      gate_pk8<2>(a, gp(gates,2,11));
      gate_pk8<4>(a, gp(gates,2,12));
      gate_lane8<0xB1>(a, gp(gates,2,8), s1);
      gate_lane8<0x4E>(a, gp(gates,2,9), s2);
      const int pj = physb(jb);
      #pragma unroll
      for (int c = 0; c < 8; ++c) lds[pj ^ pb3<10,11,12>(c)] = a[c];
    }
    __syncthreads();
    // ---- R2: c->j2-4 (gg2,3,4); t0,t1->j0,j1 (dpp gg0,1); t2-9->j5-12 ----
    {
      const int jb = (t&3) | ((t>>2)<<5);
      const int pj = physb(jb);
      #pragma unroll
      for (int c = 0; c < 8; ++c) a[c] = lds[pj ^ pb3<2,3,4>(c)];
      gate_pk8<1>(a, gp(gates,2,2));
      gate_pk8<2>(a, gp(gates,2,3));
      gate_pk8<4>(a, gp(gates,2,4));
      gate_lane8<0xB1>(a, gp(gates,2,0), s1);
      gate_lane8<0x4E>(a, gp(gates,2,1), s2);
      #pragma unroll
      for (int c = 0; c < 8; ++c) lds[pj ^ pb3<2,3,4>(c)] = a[c];
    }
    __syncthreads();
    // ---- R3: c->j5-7 (gg5,6,7); t0-4->j0-4, t5-9->j8-12; store ----
    {
      const int jb = (t&31) | (((t>>5)&31)<<8);
      const int pj = physb(jb);
      #pragma unroll
      for (int c = 0; c < 8; ++c) a[c] = lds[pj ^ pb3<5,6,7>(c)];
      gate_pk8<1>(a, gp(gates,2,5));
      gate_pk8<2>(a, gp(gates,2,6));
      gate_pk8<4>(a, gp(gates,2,7));
      #pragma unroll
      for (int c = 0; c < 8; ++c){
        const int j = jb | dep3<5,6,7>(c);
        st[stBase + (unsigned)(j | (f<<13))] = pack_bf2(a[c]);
      }
    }
  }
  else {
    // ---- P4: single round. t0,t1->j8,j9 (dpp gg13,14); c->gg15,16,17; head ----
    {
      const int jb = ((t&1)<<8)|(((t>>1)&1)<<9)|((t>>2)&255);
      const unsigned gg0 = (unsigned)((jb&255) | ((jb>>8)<<13) | (f<<8));
      const unsigned gb = stBase + gg0;
      #pragma unroll
      for (int c = 0; c < 8; ++c) a[c] = unpack_bf2(st[gb + ((unsigned)c<<15)]);
      gate_pk8<1>(a, gp(gates,2,15));
      gate_pk8<2>(a, gp(gates,2,16));
      gate_pk8<4>(a, gp(gates,2,17));
      gate_lane8<0xB1>(a, gp(gates,2,13), s1);
      gate_lane8<0x4E>(a, gp(gates,2,14), s2);
      // fused head: coef(gg) = sum_w hw[w]*(1-2*bit_{17-w}(gg))
      float cb = 0.f;
      #pragma unroll
      for (int k = 0; k < 18; ++k){
        const float hw = head_w[17-k];
        cb += ((gg0 >> k) & 1) ? -hw : hw;
      }
      // c bits -> gg{15,16,17} -> wires {2,1,0}
      const float d0 = -2.f*head_w[2], d1 = -2.f*head_w[1], d2 = -2.f*head_w[0];
      float acc = 0.f;
      #pragma unroll
      for (int c = 0; c < 8; ++c){
        float coef = cb;
        if (c & 1) coef += d0;
        if (c & 2) coef += d1;
        if (c & 4) coef += d2;
        acc += coef * (a[c].x*a[c].x + a[c].y*a[c].y);
      }
      #pragma unroll
      for (int off = 32; off; off >>= 1) acc += __shfl_down(acc, off);
      float* red = reinterpret_cast<float*>(lds);
      if ((t & 63) == 0) red[t >> 6] = acc;
      __syncthreads();
      if (t == 0){
        float s = 0.f;
        #pragma unroll
        for (int i = 0; i < 16; ++i) s += red[i];
        partials[bg * 32 + f] = s;
      }
    }
  }
}

__global__ void qprep(const float* __restrict__ params, float* __restrict__ gates){
  const int tid = threadIdx.x;
  if (tid < 54){
    const float xx = params[tid*3+0]*0.5f, yy = params[tid*3+1]*0.5f, zz = params[tid*3+2]*0.5f;
    float sx,cx,sy,cy,sz,cz;
    sincosf(xx,&sx,&cx); sincosf(yy,&sy,&cy); sincosf(zz,&sz,&cz);
    float* g = gates + tid*4;
    g[0] =  cz*cy*cx + sz*sy*sx;   // a_r (u00)
    g[1] =  cz*sy*sx - sz*cy*cx;   // a_i
    g[2] = -cz*sy*cx - sz*cy*sx;   // b_r (u01)
    g[3] =  sz*sy*cx - cz*cy*sx;   // b_i
  }
}

__global__ void qfinal(const float* __restrict__ partials, const float* __restrict__ head_b,
                       float* __restrict__ out, int B){
  const int b = threadIdx.x + blockIdx.x * blockDim.x;
  if (b < B){
    float s = head_b[0];
    #pragma unroll
    for (int i = 0; i < 32; ++i) s += partials[b*32 + i];
    out[b] = s;
  }
}

extern "C" void kernel_launch(void* const* d_in, const int* in_sizes, int n_in,
                              void* d_out, int out_size, void* d_ws, size_t ws_size,
                              hipStream_t stream){
  const float* sr     = (const float*)d_in[0];
  const float* si     = (const float*)d_in[1];
  const float* params = (const float*)d_in[2];
  const float* head_w = (const float*)d_in[3];
  const float* head_b = (const float*)d_in[4];
  float* out = (float*)d_out;
  const int B = in_sizes[0] >> DBITS;   // 128

  float*    gates    = (float*)d_ws;                        // 54*4 floats
  float*    partials = (float*)((char*)d_ws + 4096);        // B*32 floats
  unsigned* st       = (unsigned*)((char*)d_ws + 24576);    // bf16-packed state chunk

  size_t stBytes = ws_size > 24576 ? ws_size - 24576 : 0;
  int maxChunk = (int)(stBytes / ((size_t)(1 << DBITS) * 4));
  if (maxChunk > B) maxChunk = B;
  if (maxChunk < 1) maxChunk = 1;

  qprep<<<dim3(1), dim3(64), 0, stream>>>(params, gates);

  for (int b0 = 0; b0 < B; b0 += maxChunk){
    const int c = (B - b0 < maxChunk) ? (B - b0) : maxChunk;
    dim3 grid(c * 32), blk(1024);
    qpass<1><<<grid, blk, 0, stream>>>(sr, si, st, gates, head_w, partials, b0);
    qpass<2><<<grid, blk, 0, stream>>>(sr, si, st, gates, head_w, partials, b0);
    qpass<3><<<grid, blk, 0, stream>>>(sr, si, st, gates, head_w, partials, b0);
    qpass<4><<<grid, blk, 0, stream>>>(sr, si, st, gates, head_w, partials, b0);
  }
  qfinal<<<dim3(1), dim3(128), 0, stream>>>(partials, head_b, out, B);
}